// Round 9
// baseline (610.345 us; speedup 1.0000x reference)
//
#include <hip/hip_runtime.h>
#include <hip/hip_bf16.h>
#include <math.h>

// ---- problem constants ----
#define BATCH   2
#define SEQLEN  1024
#define DMODEL  1024
#define DINNER  2048
#define DSTATE  64
#define DTRANK  64
#define NLAYERS 2
#define BL      (BATCH * SEQLEN)          // 2048 rows
#define XZ_N    (2 * DINNER)              // 4096
#define XDBL_N  (DTRANK + 2 * DSTATE)     // 192
#define NCH     16                        // scan chunks per sequence
#define CLEN    (SEQLEN / NCH)            // 64 steps per chunk
#define SKN     8                         // x_proj split-K factor
#define SKC     (DINNER / SKN)            // 256 K per chunk

typedef __hip_bfloat16 bf16;
typedef short bf16x8 __attribute__((ext_vector_type(8)));
typedef float f32x4  __attribute__((ext_vector_type(4)));

// async global->LDS, 16B per lane
__device__ __forceinline__ void gload16(const void* g, void* l) {
    __builtin_amdgcn_global_load_lds(
        (__attribute__((address_space(1))) void*)(g),
        (__attribute__((address_space(3))) void*)(l), 16, 0, 0);
}

// rotate-reduce over each 16-lane row (row_ror:1/2/4/8, VALU-only DPP).
__device__ __forceinline__ float ror_sum16(float x) {
    float r = x;
    int v;
    v = __builtin_amdgcn_update_dpp(0, __float_as_int(r), 0x121, 0xf, 0xf, true); r += __int_as_float(v);
    v = __builtin_amdgcn_update_dpp(0, __float_as_int(r), 0x122, 0xf, 0xf, true); r += __int_as_float(v);
    v = __builtin_amdgcn_update_dpp(0, __float_as_int(r), 0x124, 0xf, 0xf, true); r += __int_as_float(v);
    v = __builtin_amdgcn_update_dpp(0, __float_as_int(r), 0x128, 0xf, 0xf, true); r += __int_as_float(v);
    return r;
}

// ---------------------------------------------------------------------------
// bf16 MFMA GEMM: C[M,N] = A[M,K] * W[N,K]^T, f32 accum. 128x128 tile, BK=32.
// ---------------------------------------------------------------------------
template<bool WRITE_BF>
__global__ __launch_bounds__(256) void gemm_mfma(
    const bf16* __restrict__ A, int lda,
    const bf16* __restrict__ W, int ldw,
    float* __restrict__ C, bf16* __restrict__ Cb, int ldc, int K)
{
    __shared__ short As[128 * 32];
    __shared__ short Ws[128 * 32];
    const int tid = threadIdx.x;
    const int w = tid >> 6, l = tid & 63;
    const int m0 = blockIdx.y * 128, n0 = blockIdx.x * 128;
    const int wm = (w & 1) * 64, wn = (w >> 1) * 64;

    const int srow = w * 16 + (l >> 2);
    const int scol = (l & 3) * 8;
    const bf16* Ag = A + (size_t)(m0 + srow) * lda + scol;
    const bf16* Wg = W + (size_t)(n0 + srow) * ldw + scol;
    short* Asb = &As[w * 512];
    short* Wsb = &Ws[w * 512];

    const int fr = l & 15, fq = l >> 4;
    f32x4 acc[4][4] = {};

    for (int k0 = 0; k0 < K; k0 += 32) {
        gload16(Ag + k0,                      Asb);
        gload16(Ag + (size_t)64 * lda + k0,   Asb + 64 * 32);
        gload16(Wg + k0,                      Wsb);
        gload16(Wg + (size_t)64 * ldw + k0,   Wsb + 64 * 32);
        __syncthreads();

        bf16x8 af[4], bfr[4];
#pragma unroll
        for (int m = 0; m < 4; ++m)
            af[m] = *(const bf16x8*)&As[(wm + m * 16 + fr) * 32 + fq * 8];
#pragma unroll
        for (int n = 0; n < 4; ++n)
            bfr[n] = *(const bf16x8*)&Ws[(wn + n * 16 + fr) * 32 + fq * 8];
#pragma unroll
        for (int m = 0; m < 4; ++m)
#pragma unroll
            for (int n = 0; n < 4; ++n)
                acc[m][n] = __builtin_amdgcn_mfma_f32_16x16x32_bf16(
                    af[m], bfr[n], acc[m][n], 0, 0, 0);
        __syncthreads();
    }

#pragma unroll
    for (int m = 0; m < 4; ++m) {
        const int grow = m0 + wm + m * 16 + fq * 4;
#pragma unroll
        for (int n = 0; n < 4; ++n) {
            const int gcol = n0 + wn + n * 16 + fr;
#pragma unroll
            for (int j = 0; j < 4; ++j) {
                float v = acc[m][n][j];
                C[(size_t)(grow + j) * ldc + gcol] = v;
                if (WRITE_BF)
                    Cb[(size_t)(grow + j) * ldc + gcol] = __float2bfloat16(v);
            }
        }
    }
}

// ---------------------------------------------------------------------------
// bf16 MFMA split-K GEMM for x_proj: A[2048,2048]*W[192,2048]^T.
// 128x64 tile, 4 waves (2x2), 4x2 frags/wave, BK=32, grid (3,16,SKN).
// ---------------------------------------------------------------------------
__global__ __launch_bounds__(256) void gemm_xp_mfma(
    const bf16* __restrict__ A,
    const bf16* __restrict__ W,
    float* __restrict__ Cp)
{
    __shared__ short As[128 * 32];
    __shared__ short Bs[64 * 32];
    const int tid = threadIdx.x;
    const int w = tid >> 6, l = tid & 63;
    const int m0 = blockIdx.y * 128, n0 = blockIdx.x * 64;
    const int kb = blockIdx.z * SKC;
    const int wm = (w & 1) * 64, wn = (w >> 1) * 32;

    const int srow = w * 16 + (l >> 2);      // 0..63
    const int scol = (l & 3) * 8;
    const bf16* Ag = A + (size_t)(m0 + srow) * DINNER + kb + scol;
    const bf16* Wg = W + (size_t)(n0 + srow) * DINNER + kb + scol;
    short* Asb = &As[w * 512];
    short* Bsb = &Bs[w * 512];

    const int fr = l & 15, fq = l >> 4;
    f32x4 acc[4][2] = {};

    for (int k0 = 0; k0 < SKC; k0 += 32) {
        gload16(Ag + k0,                       Asb);
        gload16(Ag + (size_t)64 * DINNER + k0, Asb + 64 * 32);
        gload16(Wg + k0,                       Bsb);
        __syncthreads();

        bf16x8 af[4], bfr[2];
#pragma unroll
        for (int m = 0; m < 4; ++m)
            af[m] = *(const bf16x8*)&As[(wm + m * 16 + fr) * 32 + fq * 8];
#pragma unroll
        for (int n = 0; n < 2; ++n)
            bfr[n] = *(const bf16x8*)&Bs[(wn + n * 16 + fr) * 32 + fq * 8];
#pragma unroll
        for (int m = 0; m < 4; ++m)
#pragma unroll
            for (int n = 0; n < 2; ++n)
                acc[m][n] = __builtin_amdgcn_mfma_f32_16x16x32_bf16(
                    af[m], bfr[n], acc[m][n], 0, 0, 0);
        __syncthreads();
    }

    float* Cz = Cp + (size_t)blockIdx.z * BL * XDBL_N;
#pragma unroll
    for (int m = 0; m < 4; ++m) {
        const int grow = m0 + wm + m * 16 + fq * 4;
#pragma unroll
        for (int n = 0; n < 2; ++n) {
            const int gcol = n0 + wn + n * 16 + fr;
#pragma unroll
            for (int j = 0; j < 4; ++j)
                Cz[(size_t)(grow + j) * XDBL_N + gcol] = acc[m][n][j];
        }
    }
}

// fixed-order split-K reduce: xd = sum_z Cp[z]
__global__ __launch_bounds__(256) void reduce_xd(
    const float* __restrict__ Cp, float* __restrict__ xd)
{
    const int i = blockIdx.x * 256 + threadIdx.x;    // float4 index
    const int n4 = BL * XDBL_N / 4;
    if (i >= n4) return;
    const float4* p = (const float4*)Cp + i;
    float4 s = p[0];
#pragma unroll
    for (int z = 1; z < SKN; ++z) {
        float4 v = p[(size_t)z * n4];
        s.x += v.x; s.y += v.y; s.z += v.z; s.w += v.w;
    }
    ((float4*)xd)[i] = s;
}

// ---------------------------------------------------------------------------
// f32 tiled GEMM, 64x64 tile (dt_proj only, K=64).
// EPI 1: softplus(acc+bias) -> dtT[b][d][t]; *u -> dtuT[b][d][t].
// ---------------------------------------------------------------------------
template<int EPI>
__global__ __launch_bounds__(256) void gemm_nt(
    const float* __restrict__ A, int lda,
    const float* __restrict__ W,
    const float* __restrict__ bias,
    float* __restrict__ C, int ldc, int K,
    const float* __restrict__ u,
    float* __restrict__ dtT, float* __restrict__ dtuT)
{
    __shared__ float As[16][68];
    __shared__ float Ws[16][68];
    const int tid = threadIdx.x;
    const int tx = tid & 15, ty = tid >> 4;
    const int m0 = blockIdx.y * 64, n0 = blockIdx.x * 64;
    const int lr = tid >> 2;
    const int lk = (tid & 3) << 2;

    const float* Ap = A + (size_t)(m0 + lr) * lda + lk;
    const float* Wp = W + (size_t)(n0 + lr) * K + lk;

    float acc[4][4] = {};

    for (int k0 = 0; k0 < K; k0 += 16) {
        float4 av = *(const float4*)(Ap + k0);
        float4 wv = *(const float4*)(Wp + k0);
        As[lk + 0][lr] = av.x; As[lk + 1][lr] = av.y;
        As[lk + 2][lr] = av.z; As[lk + 3][lr] = av.w;
        Ws[lk + 0][lr] = wv.x; Ws[lk + 1][lr] = wv.y;
        Ws[lk + 2][lr] = wv.z; Ws[lk + 3][lr] = wv.w;
        __syncthreads();
#pragma unroll
        for (int kk = 0; kk < 16; ++kk) {
            float4 a = *(const float4*)&As[kk][ty << 2];
            float4 b = *(const float4*)&Ws[kk][tx << 2];
            acc[0][0] += a.x * b.x; acc[0][1] += a.x * b.y;
            acc[0][2] += a.x * b.z; acc[0][3] += a.x * b.w;
            acc[1][0] += a.y * b.x; acc[1][1] += a.y * b.y;
            acc[1][2] += a.y * b.z; acc[1][3] += a.y * b.w;
            acc[2][0] += a.z * b.x; acc[2][1] += a.z * b.y;
            acc[2][2] += a.z * b.z; acc[2][3] += a.z * b.w;
            acc[3][0] += a.w * b.x; acc[3][1] += a.w * b.y;
            acc[3][2] += a.w * b.z; acc[3][3] += a.w * b.w;
        }
        __syncthreads();
    }

    const int n = n0 + (tx << 2);
    const int b = m0 >> 10;                       // tiles never straddle batch
    const int t0 = (m0 & (SEQLEN - 1)) + (ty << 2);

    if (EPI == 0) {
#pragma unroll
        for (int i = 0; i < 4; ++i) {
            float4 v = make_float4(acc[i][0], acc[i][1], acc[i][2], acc[i][3]);
            *(float4*)&C[(size_t)(m0 + (ty << 2) + i) * ldc + n] = v;
        }
    } else {
        float sp[4][4];
        float uu[4][4];
#pragma unroll
        for (int i = 0; i < 4; ++i) {
            float4 u4 = *(const float4*)&u[(size_t)(m0 + (ty << 2) + i) * DINNER + n];
            uu[i][0] = u4.x; uu[i][1] = u4.y; uu[i][2] = u4.z; uu[i][3] = u4.w;
#pragma unroll
            for (int j = 0; j < 4; ++j) {
                float v = acc[i][j] + bias[n + j];
                sp[i][j] = v > 20.f ? v : log1pf(expf(v));
            }
        }
#pragma unroll
        for (int j = 0; j < 4; ++j) {
            const int col = n + j;
            float4 vd = make_float4(sp[0][j], sp[1][j], sp[2][j], sp[3][j]);
            float4 vg = make_float4(sp[0][j] * uu[0][j], sp[1][j] * uu[1][j],
                                    sp[2][j] * uu[2][j], sp[3][j] * uu[3][j]);
            *(float4*)&dtT [((size_t)b * DINNER + col) * SEQLEN + t0] = vd;
            *(float4*)&dtuT[((size_t)b * DINNER + col) * SEQLEN + t0] = vg;
        }
    }
}

// ---------------------------------------------------------------------------
__global__ __launch_bounds__(256) void cvt_bf16_kernel(
    const float* __restrict__ in, bf16* __restrict__ out, int n4)
{
    int i = blockIdx.x * 256 + threadIdx.x;
    if (i >= n4) return;
    float4 v = ((const float4*)in)[i];
    union { bf16 b[4]; uint2 u; } r;
    r.b[0] = __float2bfloat16(v.x); r.b[1] = __float2bfloat16(v.y);
    r.b[2] = __float2bfloat16(v.z); r.b[3] = __float2bfloat16(v.w);
    ((uint2*)out)[i] = r.u;
}

// ---------------------------------------------------------------------------
// conv + silu; writes f32 u and bf16 u (for the MFMA x_proj)
// ---------------------------------------------------------------------------
__global__ __launch_bounds__(256) void conv_silu_kernel(
    const float* __restrict__ xz, const float* __restrict__ cw,
    const float* __restrict__ cb, float* __restrict__ u,
    bf16* __restrict__ u_bf)
{
    int idx = blockIdx.x * 256 + threadIdx.x;
    if (idx >= BL * DINNER) return;
    int d = idx & (DINNER - 1);
    int m = idx >> 11;
    int t = m & (SEQLEN - 1);
    float acc = cb[d];
#pragma unroll
    for (int k = 0; k < 4; ++k) {
        int tt = t - 3 + k;
        if (tt >= 0)
            acc += xz[(size_t)(m - 3 + k) * XZ_N + d] * cw[d * 4 + k];
    }
    float s = acc / (1.f + expf(-acc));
    u[idx] = s;
    u_bf[idx] = __float2bfloat16(s);
}

// ---------------------------------------------------------------------------
// Chunked selective scan, 16-lane-group structure, LDS-free.
// Block = 4 waves; each wave = 4 channels (16 lanes/channel, 4 states/lane).
// B/C read directly from xd (coalesced 256B per lane-group; L1/L2-resident).
// ---------------------------------------------------------------------------
__global__ __launch_bounds__(256) void scan_pass1(
    const float* __restrict__ dtT, const float* __restrict__ dtuT,
    const float* __restrict__ xd, const float* __restrict__ A_log,
    float* __restrict__ q, float* __restrict__ P)
{
    const int tid = threadIdx.x;
    const int bx = blockIdx.x;
    const int dg = bx & 127;                 // d-group (16 channels)
    const int c  = (bx >> 7) & (NCH - 1);
    const int b  = bx >> 11;
    const int m0 = b * SEQLEN + c * CLEN;    // xd row base

    const int w = tid >> 6, l = tid & 63;
    const int d  = dg * 16 + w * 4 + (l >> 4);
    const int s0 = (l & 15) * 4;

    float4 Al = *(const float4*)&A_log[d * DSTATE + s0];
    const float Av0 = -expf(Al.x), Av1 = -expf(Al.y);
    const float Av2 = -expf(Al.z), Av3 = -expf(Al.w);

    const float* dtp  = dtT  + ((size_t)b * DINNER + d) * SEQLEN + c * CLEN;
    const float* dtup = dtuT + ((size_t)b * DINNER + d) * SEQLEN + c * CLEN;
    const float* Bp   = xd + (size_t)m0 * XDBL_N + DTRANK + s0;

    float h0 = 0.f, h1 = 0.f, h2 = 0.f, h3 = 0.f;
    float sdt = 0.f;
#pragma unroll
    for (int t4 = 0; t4 < CLEN; t4 += 4) {
        float4 d4 = *(const float4*)(dtp + t4);
        float4 g4 = *(const float4*)(dtup + t4);
#pragma unroll
        for (int k = 0; k < 4; ++k) {
            float dts = (k == 0) ? d4.x : (k == 1) ? d4.y : (k == 2) ? d4.z : d4.w;
            float gts = (k == 0) ? g4.x : (k == 1) ? g4.y : (k == 2) ? g4.z : g4.w;
            float4 Bv = *(const float4*)(Bp + (size_t)(t4 + k) * XDBL_N);
            sdt += dts;
            h0 = h0 * __expf(dts * Av0) + gts * Bv.x;
            h1 = h1 * __expf(dts * Av1) + gts * Bv.y;
            h2 = h2 * __expf(dts * Av2) + gts * Bv.z;
            h3 = h3 * __expf(dts * Av3) + gts * Bv.w;
        }
    }
    const size_t o = (((size_t)b * DINNER + d) * NCH + c) * DSTATE + s0;
    *(float4*)&q[o] = make_float4(h0, h1, h2, h3);
    *(float4*)&P[o] = make_float4(__expf(Av0 * sdt), __expf(Av1 * sdt),
                                  __expf(Av2 * sdt), __expf(Av3 * sdt));
}

__global__ __launch_bounds__(256) void scan_pass2(
    float* __restrict__ q, const float* __restrict__ P)
{
    const int idx = blockIdx.x * 256 + threadIdx.x;
    const int bd = idx >> 6, s = idx & 63;
    float H = 0.f;
    size_t o = (size_t)bd * NCH * DSTATE + s;
    for (int c = 0; c < NCH; ++c, o += DSTATE) {
        float qq = q[o], pp = P[o];
        q[o] = H;
        H = qq + pp * H;
    }
}

__global__ __launch_bounds__(256) void scan_pass3(
    const float* __restrict__ dtT, const float* __restrict__ dtuT,
    const float* __restrict__ xd, const float* __restrict__ A_log,
    const float* __restrict__ Hs, float* __restrict__ y)
{
    const int tid = threadIdx.x;
    const int bx = blockIdx.x;
    const int dg = bx & 127;
    const int c  = (bx >> 7) & (NCH - 1);
    const int b  = bx >> 11;
    const int m0 = b * SEQLEN + c * CLEN;

    const int w = tid >> 6, l = tid & 63;
    const int d  = dg * 16 + w * 4 + (l >> 4);
    const int s0 = (l & 15) * 4;
    const bool lead = (l & 15) == 0;

    float4 Al = *(const float4*)&A_log[d * DSTATE + s0];
    const float Av0 = -expf(Al.x), Av1 = -expf(Al.y);
    const float Av2 = -expf(Al.z), Av3 = -expf(Al.w);

    const float* dtp  = dtT  + ((size_t)b * DINNER + d) * SEQLEN + c * CLEN;
    const float* dtup = dtuT + ((size_t)b * DINNER + d) * SEQLEN + c * CLEN;
    const float* Bp   = xd + (size_t)m0 * XDBL_N + DTRANK + s0;
    const float* Cp   = Bp + DSTATE;
    float* yp = y + (size_t)m0 * DINNER + d;

    float4 h4 = *(const float4*)&Hs[(((size_t)b * DINNER + d) * NCH + c) * DSTATE + s0];
    float h0 = h4.x, h1 = h4.y, h2 = h4.z, h3 = h4.w;

#pragma unroll
    for (int t4 = 0; t4 < CLEN; t4 += 4) {
        float4 d4 = *(const float4*)(dtp + t4);
        float4 g4 = *(const float4*)(dtup + t4);
#pragma unroll
        for (int k = 0; k < 4; ++k) {
            float dts = (k == 0) ? d4.x : (k == 1) ? d4.y : (k == 2) ? d4.z : d4.w;
            float gts = (k == 0) ? g4.x : (k == 1) ? g4.y : (k == 2) ? g4.z : g4.w;
            float4 Bv = *(const float4*)(Bp + (size_t)(t4 + k) * XDBL_N);
            float4 Cv = *(const float4*)(Cp + (size_t)(t4 + k) * XDBL_N);
            h0 = h0 * __expf(dts * Av0) + gts * Bv.x;
            h1 = h1 * __expf(dts * Av1) + gts * Bv.y;
            h2 = h2 * __expf(dts * Av2) + gts * Bv.z;
            h3 = h3 * __expf(dts * Av3) + gts * Bv.w;
            float v = h0 * Cv.x + h1 * Cv.y + h2 * Cv.z + h3 * Cv.w;
            float r = ror_sum16(v);
            if (lead) yp[(t4 + k) * DINNER] = r;
        }
    }
}

// ---------------------------------------------------------------------------
// Gate + skip: y_bf = (y_scan + u*Dk) * silu(z)
// ---------------------------------------------------------------------------
__global__ __launch_bounds__(256) void gate_kernel(
    const float* __restrict__ y, const float* __restrict__ xz,
    const float* __restrict__ u, const float* __restrict__ D_skip,
    bf16* __restrict__ yb16)
{
    int idx = blockIdx.x * 256 + threadIdx.x;
    if (idx >= BL * DINNER) return;
    int d = idx & (DINNER - 1);
    int m = idx >> 11;
    float z = xz[(size_t)m * XZ_N + DINNER + d];
    float val = (y[idx] + u[idx] * D_skip[d]) * z / (1.f + expf(-z));
    yb16[idx] = __float2bfloat16(val);
}

// ---------------------------------------------------------------------------
extern "C" void kernel_launch(void* const* d_in, const int* in_sizes, int n_in,
                              void* d_out, int out_size, void* d_ws, size_t ws_size,
                              hipStream_t stream)
{
    const float* x     = (const float*)d_in[0];
    const float* in_w  = (const float*)d_in[1];
    const float* cw    = (const float*)d_in[2];
    const float* cb    = (const float*)d_in[3];
    const float* xp_w  = (const float*)d_in[4];
    const float* dt_w  = (const float*)d_in[5];
    const float* dt_b  = (const float*)d_in[6];
    const float* A_log = (const float*)d_in[7];
    const float* D_sk  = (const float*)d_in[8];
    const float* out_w = (const float*)d_in[9];
    float* out_final = (float*)d_out;

    float* ws = (float*)d_ws;
    float* xz    = ws;                                // [2048,4096]
    float* ub    = xz   + (size_t)BL * XZ_N;          // [2048,2048]
    float* xd    = ub   + (size_t)BL * DINNER;        // [2048,192]
    float* yb    = xd   + (size_t)BL * XDBL_N;        // [2048,2048] (also SK partials)
    float* lay   = yb   + (size_t)BL * DINNER;        // [2048,1024]
    float* dtT   = lay  + (size_t)BL * DMODEL;        // [2,2048,1024]
    float* dtuT  = dtT  + (size_t)BL * DINNER;        // [2,2048,1024]

    float* skp = yb;   // split-K partials [8][2048][192] = 12.6 MB <= yb's 16.8 MB

    bf16* bp = (bf16*)(dtuT + (size_t)BL * DINNER);
    bf16* inw_bf  = bp;  bp += (size_t)NLAYERS * XZ_N * DMODEL;
    bf16* outw_bf = bp;  bp += (size_t)NLAYERS * DMODEL * DINNER;
    bf16* xpw_bf  = bp;  bp += (size_t)NLAYERS * XDBL_N * DINNER;
    bf16* xin_bf  = bp;  bp += (size_t)BL * DMODEL;
    bf16* y_bf    = bp;  bp += (size_t)BL * DINNER;
    bf16* u_bf    = bp;  bp += (size_t)BL * DINNER;

    float* qbuf = (float*)bp;                              // [4096,16,64]
    float* Pbuf = qbuf + (size_t)BATCH * DINNER * NCH * DSTATE;

    {
        int n4 = NLAYERS * XZ_N * DMODEL / 4;
        cvt_bf16_kernel<<<(n4 + 255) / 256, 256, 0, stream>>>(in_w, inw_bf, n4);
        n4 = NLAYERS * DMODEL * DINNER / 4;
        cvt_bf16_kernel<<<(n4 + 255) / 256, 256, 0, stream>>>(out_w, outw_bf, n4);
        n4 = NLAYERS * XDBL_N * DINNER / 4;
        cvt_bf16_kernel<<<(n4 + 255) / 256, 256, 0, stream>>>(xp_w, xpw_bf, n4);
        n4 = BL * DMODEL / 4;
        cvt_bf16_kernel<<<(n4 + 255) / 256, 256, 0, stream>>>(x, xin_bf, n4);
    }

    for (int layer = 0; layer < NLAYERS; ++layer) {
        float* outp = (layer == NLAYERS - 1) ? out_final : lay;

        // 1. xz = xin @ in_w^T  (bf16 MFMA)
        gemm_mfma<false><<<dim3(XZ_N / 128, BL / 128), 256, 0, stream>>>(
            xin_bf, DMODEL, inw_bf + (size_t)layer * XZ_N * DMODEL,
            DMODEL, xz, nullptr, XZ_N, DMODEL);

        // 2. u = silu(dwconv(xz[:, :2048]))  (f32 + bf16 copies)
        conv_silu_kernel<<<(BL * DINNER) / 256, 256, 0, stream>>>(
            xz, cw + (size_t)layer * DINNER * 4, cb + (size_t)layer * DINNER,
            ub, u_bf);

        // 3. x_dbl = u @ xp_w^T  (bf16 MFMA split-K + deterministic f32 reduce)
        gemm_xp_mfma<<<dim3(XDBL_N / 64, BL / 128, SKN), 256, 0, stream>>>(
            u_bf, xpw_bf + (size_t)layer * XDBL_N * DINNER, skp);
        reduce_xd<<<(BL * XDBL_N / 4 + 255) / 256, 256, 0, stream>>>(skp, xd);

        // 4. dt = softplus(...); writes dtT and dtuT (= dt*u) transposed
        gemm_nt<1><<<dim3(DINNER / 64, BL / 64), 256, 0, stream>>>(
            xd, XDBL_N, dt_w + (size_t)layer * DINNER * DTRANK,
            dt_b + (size_t)layer * DINNER, nullptr, DINNER, DTRANK,
            ub, dtT, dtuT);

        // 5. chunked selective scan -> yb
        scan_pass1<<<BATCH * NCH * (DINNER / 16), 256, 0, stream>>>(
            dtT, dtuT, xd, A_log + (size_t)layer * DINNER * DSTATE, qbuf, Pbuf);
        scan_pass2<<<BATCH * DINNER * DSTATE / 256, 256, 0, stream>>>(qbuf, Pbuf);
        scan_pass3<<<BATCH * NCH * (DINNER / 16), 256, 0, stream>>>(
            dtT, dtuT, xd, A_log + (size_t)layer * DINNER * DSTATE, qbuf, yb);

        // 6. y_bf = (yb + u*Dk) * silu(z)
        gate_kernel<<<(BL * DINNER) / 256, 256, 0, stream>>>(
            yb, xz, ub, D_sk + (size_t)layer * DINNER, y_bf);

        // 7. out = y @ out_w^T  (bf16 MFMA)
        if (layer == NLAYERS - 1)
            gemm_mfma<false><<<dim3(DMODEL / 128, BL / 128), 256, 0, stream>>>(
                y_bf, DINNER, outw_bf + (size_t)layer * DMODEL * DINNER,
                DINNER, outp, nullptr, DMODEL, DINNER);
        else
            gemm_mfma<true><<<dim3(DMODEL / 128, BL / 128), 256, 0, stream>>>(
                y_bf, DINNER, outw_bf + (size_t)layer * DMODEL * DINNER,
                DINNER, outp, xin_bf, DMODEL, DINNER);
    }
}

// Round 10
// 542.662 us; speedup vs baseline: 1.1247x; 1.1247x over previous
//
#include <hip/hip_runtime.h>
#include <hip/hip_bf16.h>
#include <math.h>

// ---- problem constants ----
#define BATCH   2
#define SEQLEN  1024
#define DMODEL  1024
#define DINNER  2048
#define DSTATE  64
#define DTRANK  64
#define NLAYERS 2
#define BL      (BATCH * SEQLEN)          // 2048 rows
#define XZ_N    (2 * DINNER)              // 4096
#define XDBL_N  (DTRANK + 2 * DSTATE)     // 192
#define NCH     16                        // scan chunks per sequence
#define CLEN    (SEQLEN / NCH)            // 64 steps per chunk
#define SKN     8                         // x_proj split-K factor
#define SKC     (DINNER / SKN)            // 256 K per chunk

typedef __hip_bfloat16 bf16;
typedef short bf16x8 __attribute__((ext_vector_type(8)));
typedef float f32x4  __attribute__((ext_vector_type(4)));

// async global->LDS, 16B per lane
__device__ __forceinline__ void gload16(const void* g, void* l) {
    __builtin_amdgcn_global_load_lds(
        (__attribute__((address_space(1))) void*)(g),
        (__attribute__((address_space(3))) void*)(l), 16, 0, 0);
}

// rotate-reduce over each 16-lane row (row_ror:1/2/4/8, VALU-only DPP).
__device__ __forceinline__ float ror_sum16(float x) {
    float r = x;
    int v;
    v = __builtin_amdgcn_update_dpp(0, __float_as_int(r), 0x121, 0xf, 0xf, true); r += __int_as_float(v);
    v = __builtin_amdgcn_update_dpp(0, __float_as_int(r), 0x122, 0xf, 0xf, true); r += __int_as_float(v);
    v = __builtin_amdgcn_update_dpp(0, __float_as_int(r), 0x124, 0xf, 0xf, true); r += __int_as_float(v);
    v = __builtin_amdgcn_update_dpp(0, __float_as_int(r), 0x128, 0xf, 0xf, true); r += __int_as_float(v);
    return r;
}

// ---------------------------------------------------------------------------
// bf16 MFMA GEMM: C[M,N] = A[M,K] * W[N,K]^T, f32 accum. 128x128 tile, BK=32.
// ---------------------------------------------------------------------------
template<bool WRITE_BF>
__global__ __launch_bounds__(256) void gemm_mfma(
    const bf16* __restrict__ A, int lda,
    const bf16* __restrict__ W, int ldw,
    float* __restrict__ C, bf16* __restrict__ Cb, int ldc, int K)
{
    __shared__ short As[128 * 32];
    __shared__ short Ws[128 * 32];
    const int tid = threadIdx.x;
    const int w = tid >> 6, l = tid & 63;
    const int m0 = blockIdx.y * 128, n0 = blockIdx.x * 128;
    const int wm = (w & 1) * 64, wn = (w >> 1) * 64;

    const int srow = w * 16 + (l >> 2);
    const int scol = (l & 3) * 8;
    const bf16* Ag = A + (size_t)(m0 + srow) * lda + scol;
    const bf16* Wg = W + (size_t)(n0 + srow) * ldw + scol;
    short* Asb = &As[w * 512];
    short* Wsb = &Ws[w * 512];

    const int fr = l & 15, fq = l >> 4;
    f32x4 acc[4][4] = {};

    for (int k0 = 0; k0 < K; k0 += 32) {
        gload16(Ag + k0,                      Asb);
        gload16(Ag + (size_t)64 * lda + k0,   Asb + 64 * 32);
        gload16(Wg + k0,                      Wsb);
        gload16(Wg + (size_t)64 * ldw + k0,   Wsb + 64 * 32);
        __syncthreads();

        bf16x8 af[4], bfr[4];
#pragma unroll
        for (int m = 0; m < 4; ++m)
            af[m] = *(const bf16x8*)&As[(wm + m * 16 + fr) * 32 + fq * 8];
#pragma unroll
        for (int n = 0; n < 4; ++n)
            bfr[n] = *(const bf16x8*)&Ws[(wn + n * 16 + fr) * 32 + fq * 8];
#pragma unroll
        for (int m = 0; m < 4; ++m)
#pragma unroll
            for (int n = 0; n < 4; ++n)
                acc[m][n] = __builtin_amdgcn_mfma_f32_16x16x32_bf16(
                    af[m], bfr[n], acc[m][n], 0, 0, 0);
        __syncthreads();
    }

#pragma unroll
    for (int m = 0; m < 4; ++m) {
        const int grow = m0 + wm + m * 16 + fq * 4;
#pragma unroll
        for (int n = 0; n < 4; ++n) {
            const int gcol = n0 + wn + n * 16 + fr;
#pragma unroll
            for (int j = 0; j < 4; ++j) {
                float v = acc[m][n][j];
                C[(size_t)(grow + j) * ldc + gcol] = v;
                if (WRITE_BF)
                    Cb[(size_t)(grow + j) * ldc + gcol] = __float2bfloat16(v);
            }
        }
    }
}

// ---------------------------------------------------------------------------
// bf16 MFMA split-K GEMM for x_proj: A[2048,2048]*W[192,2048]^T.
// 128x64 tile, 4 waves (2x2), 4x2 frags/wave, BK=32, grid (3,16,SKN).
// ---------------------------------------------------------------------------
__global__ __launch_bounds__(256) void gemm_xp_mfma(
    const bf16* __restrict__ A,
    const bf16* __restrict__ W,
    float* __restrict__ Cp)
{
    __shared__ short As[128 * 32];
    __shared__ short Bs[64 * 32];
    const int tid = threadIdx.x;
    const int w = tid >> 6, l = tid & 63;
    const int m0 = blockIdx.y * 128, n0 = blockIdx.x * 64;
    const int kb = blockIdx.z * SKC;
    const int wm = (w & 1) * 64, wn = (w >> 1) * 32;

    const int srow = w * 16 + (l >> 2);      // 0..63
    const int scol = (l & 3) * 8;
    const bf16* Ag = A + (size_t)(m0 + srow) * DINNER + kb + scol;
    const bf16* Wg = W + (size_t)(n0 + srow) * DINNER + kb + scol;
    short* Asb = &As[w * 512];
    short* Bsb = &Bs[w * 512];

    const int fr = l & 15, fq = l >> 4;
    f32x4 acc[4][2] = {};

    for (int k0 = 0; k0 < SKC; k0 += 32) {
        gload16(Ag + k0,                       Asb);
        gload16(Ag + (size_t)64 * DINNER + k0, Asb + 64 * 32);
        gload16(Wg + k0,                       Bsb);
        __syncthreads();

        bf16x8 af[4], bfr[2];
#pragma unroll
        for (int m = 0; m < 4; ++m)
            af[m] = *(const bf16x8*)&As[(wm + m * 16 + fr) * 32 + fq * 8];
#pragma unroll
        for (int n = 0; n < 2; ++n)
            bfr[n] = *(const bf16x8*)&Bs[(wn + n * 16 + fr) * 32 + fq * 8];
#pragma unroll
        for (int m = 0; m < 4; ++m)
#pragma unroll
            for (int n = 0; n < 2; ++n)
                acc[m][n] = __builtin_amdgcn_mfma_f32_16x16x32_bf16(
                    af[m], bfr[n], acc[m][n], 0, 0, 0);
        __syncthreads();
    }

    float* Cz = Cp + (size_t)blockIdx.z * BL * XDBL_N;
#pragma unroll
    for (int m = 0; m < 4; ++m) {
        const int grow = m0 + wm + m * 16 + fq * 4;
#pragma unroll
        for (int n = 0; n < 2; ++n) {
            const int gcol = n0 + wn + n * 16 + fr;
#pragma unroll
            for (int j = 0; j < 4; ++j)
                Cz[(size_t)(grow + j) * XDBL_N + gcol] = acc[m][n][j];
        }
    }
}

// fixed-order split-K reduce: xd = sum_z Cp[z]
__global__ __launch_bounds__(256) void reduce_xd(
    const float* __restrict__ Cp, float* __restrict__ xd)
{
    const int i = blockIdx.x * 256 + threadIdx.x;    // float4 index
    const int n4 = BL * XDBL_N / 4;
    if (i >= n4) return;
    const float4* p = (const float4*)Cp + i;
    float4 s = p[0];
#pragma unroll
    for (int z = 1; z < SKN; ++z) {
        float4 v = p[(size_t)z * n4];
        s.x += v.x; s.y += v.y; s.z += v.z; s.w += v.w;
    }
    ((float4*)xd)[i] = s;
}

// ---------------------------------------------------------------------------
// f32 tiled GEMM, 64x64 tile (dt_proj only, K=64).
// EPI 1: softplus(acc+bias) -> dtT[b][d][t]; *u -> dtuT[b][d][t].
// ---------------------------------------------------------------------------
template<int EPI>
__global__ __launch_bounds__(256) void gemm_nt(
    const float* __restrict__ A, int lda,
    const float* __restrict__ W,
    const float* __restrict__ bias,
    float* __restrict__ C, int ldc, int K,
    const float* __restrict__ u,
    float* __restrict__ dtT, float* __restrict__ dtuT)
{
    __shared__ float As[16][68];
    __shared__ float Ws[16][68];
    const int tid = threadIdx.x;
    const int tx = tid & 15, ty = tid >> 4;
    const int m0 = blockIdx.y * 64, n0 = blockIdx.x * 64;
    const int lr = tid >> 2;
    const int lk = (tid & 3) << 2;

    const float* Ap = A + (size_t)(m0 + lr) * lda + lk;
    const float* Wp = W + (size_t)(n0 + lr) * K + lk;

    float acc[4][4] = {};

    for (int k0 = 0; k0 < K; k0 += 16) {
        float4 av = *(const float4*)(Ap + k0);
        float4 wv = *(const float4*)(Wp + k0);
        As[lk + 0][lr] = av.x; As[lk + 1][lr] = av.y;
        As[lk + 2][lr] = av.z; As[lk + 3][lr] = av.w;
        Ws[lk + 0][lr] = wv.x; Ws[lk + 1][lr] = wv.y;
        Ws[lk + 2][lr] = wv.z; Ws[lk + 3][lr] = wv.w;
        __syncthreads();
#pragma unroll
        for (int kk = 0; kk < 16; ++kk) {
            float4 a = *(const float4*)&As[kk][ty << 2];
            float4 b = *(const float4*)&Ws[kk][tx << 2];
            acc[0][0] += a.x * b.x; acc[0][1] += a.x * b.y;
            acc[0][2] += a.x * b.z; acc[0][3] += a.x * b.w;
            acc[1][0] += a.y * b.x; acc[1][1] += a.y * b.y;
            acc[1][2] += a.y * b.z; acc[1][3] += a.y * b.w;
            acc[2][0] += a.z * b.x; acc[2][1] += a.z * b.y;
            acc[2][2] += a.z * b.z; acc[2][3] += a.z * b.w;
            acc[3][0] += a.w * b.x; acc[3][1] += a.w * b.y;
            acc[3][2] += a.w * b.z; acc[3][3] += a.w * b.w;
        }
        __syncthreads();
    }

    const int n = n0 + (tx << 2);
    const int b = m0 >> 10;                       // tiles never straddle batch
    const int t0 = (m0 & (SEQLEN - 1)) + (ty << 2);

    if (EPI == 0) {
#pragma unroll
        for (int i = 0; i < 4; ++i) {
            float4 v = make_float4(acc[i][0], acc[i][1], acc[i][2], acc[i][3]);
            *(float4*)&C[(size_t)(m0 + (ty << 2) + i) * ldc + n] = v;
        }
    } else {
        float sp[4][4];
        float uu[4][4];
#pragma unroll
        for (int i = 0; i < 4; ++i) {
            float4 u4 = *(const float4*)&u[(size_t)(m0 + (ty << 2) + i) * DINNER + n];
            uu[i][0] = u4.x; uu[i][1] = u4.y; uu[i][2] = u4.z; uu[i][3] = u4.w;
#pragma unroll
            for (int j = 0; j < 4; ++j) {
                float v = acc[i][j] + bias[n + j];
                sp[i][j] = v > 20.f ? v : log1pf(expf(v));
            }
        }
#pragma unroll
        for (int j = 0; j < 4; ++j) {
            const int col = n + j;
            float4 vd = make_float4(sp[0][j], sp[1][j], sp[2][j], sp[3][j]);
            float4 vg = make_float4(sp[0][j] * uu[0][j], sp[1][j] * uu[1][j],
                                    sp[2][j] * uu[2][j], sp[3][j] * uu[3][j]);
            *(float4*)&dtT [((size_t)b * DINNER + col) * SEQLEN + t0] = vd;
            *(float4*)&dtuT[((size_t)b * DINNER + col) * SEQLEN + t0] = vg;
        }
    }
}

// ---------------------------------------------------------------------------
__global__ __launch_bounds__(256) void cvt_bf16_kernel(
    const float* __restrict__ in, bf16* __restrict__ out, int n4)
{
    int i = blockIdx.x * 256 + threadIdx.x;
    if (i >= n4) return;
    float4 v = ((const float4*)in)[i];
    union { bf16 b[4]; uint2 u; } r;
    r.b[0] = __float2bfloat16(v.x); r.b[1] = __float2bfloat16(v.y);
    r.b[2] = __float2bfloat16(v.z); r.b[3] = __float2bfloat16(v.w);
    ((uint2*)out)[i] = r.u;
}

// ---------------------------------------------------------------------------
// conv + silu; writes f32 u and bf16 u (for the MFMA x_proj)
// ---------------------------------------------------------------------------
__global__ __launch_bounds__(256) void conv_silu_kernel(
    const float* __restrict__ xz, const float* __restrict__ cw,
    const float* __restrict__ cb, float* __restrict__ u,
    bf16* __restrict__ u_bf)
{
    int idx = blockIdx.x * 256 + threadIdx.x;
    if (idx >= BL * DINNER) return;
    int d = idx & (DINNER - 1);
    int m = idx >> 11;
    int t = m & (SEQLEN - 1);
    float acc = cb[d];
#pragma unroll
    for (int k = 0; k < 4; ++k) {
        int tt = t - 3 + k;
        if (tt >= 0)
            acc += xz[(size_t)(m - 3 + k) * XZ_N + d] * cw[d * 4 + k];
    }
    float s = acc / (1.f + expf(-acc));
    u[idx] = s;
    u_bf[idx] = __float2bfloat16(s);
}

// ---------------------------------------------------------------------------
// Chunked selective scan, 16-lane-group structure.
// Block = 4 waves; each wave = 4 channels (16 lanes/channel, 4 states/lane).
// pass1: B staged whole-chunk (17.4KB). pass3: B|C staged in 32-step halves
// (16.9KB) so LDS permits 8 blocks/CU (vs 4 with whole-chunk staging).
// ---------------------------------------------------------------------------
__global__ __launch_bounds__(256) void scan_pass1(
    const float* __restrict__ dtT, const float* __restrict__ dtuT,
    const float* __restrict__ xd, const float* __restrict__ A_log,
    float* __restrict__ q, float* __restrict__ P)
{
    __shared__ float Bs[64 * 68];     // [t][s] stride 68
    const int tid = threadIdx.x;
    const int bx = blockIdx.x;
    const int dg = bx & 127;                 // d-group (16 channels)
    const int c  = (bx >> 7) & (NCH - 1);
    const int b  = bx >> 11;
    const int m0 = b * SEQLEN + c * CLEN;    // xd row base

    {   // stage B: xd cols 64..127 of 64 rows -> Bs[t][s]
        const int r = tid >> 2, q4 = tid & 3;
        const float* src = xd + (size_t)(m0 + r) * XDBL_N + DTRANK + q4 * 4;
        float* dst = &Bs[r * 68 + q4 * 4];
#pragma unroll
        for (int ii = 0; ii < 4; ++ii)
            *(float4*)(dst + ii * 16) = *(const float4*)(src + ii * 16);
    }
    __syncthreads();

    const int w = tid >> 6, l = tid & 63;
    const int d  = dg * 16 + w * 4 + (l >> 4);
    const int s0 = (l & 15) * 4;

    float4 Al = *(const float4*)&A_log[d * DSTATE + s0];
    const float Av0 = -expf(Al.x), Av1 = -expf(Al.y);
    const float Av2 = -expf(Al.z), Av3 = -expf(Al.w);

    const float* dtp  = dtT  + ((size_t)b * DINNER + d) * SEQLEN + c * CLEN;
    const float* dtup = dtuT + ((size_t)b * DINNER + d) * SEQLEN + c * CLEN;

    float h0 = 0.f, h1 = 0.f, h2 = 0.f, h3 = 0.f;
    float sdt = 0.f;
#pragma unroll
    for (int t4 = 0; t4 < CLEN; t4 += 4) {
        float4 d4 = *(const float4*)(dtp + t4);
        float4 g4 = *(const float4*)(dtup + t4);
#pragma unroll
        for (int k = 0; k < 4; ++k) {
            float dts = (k == 0) ? d4.x : (k == 1) ? d4.y : (k == 2) ? d4.z : d4.w;
            float gts = (k == 0) ? g4.x : (k == 1) ? g4.y : (k == 2) ? g4.z : g4.w;
            float4 Bv = *(const float4*)&Bs[(t4 + k) * 68 + s0];
            sdt += dts;
            h0 = h0 * __expf(dts * Av0) + gts * Bv.x;
            h1 = h1 * __expf(dts * Av1) + gts * Bv.y;
            h2 = h2 * __expf(dts * Av2) + gts * Bv.z;
            h3 = h3 * __expf(dts * Av3) + gts * Bv.w;
        }
    }
    const size_t o = (((size_t)b * DINNER + d) * NCH + c) * DSTATE + s0;
    *(float4*)&q[o] = make_float4(h0, h1, h2, h3);
    *(float4*)&P[o] = make_float4(__expf(Av0 * sdt), __expf(Av1 * sdt),
                                  __expf(Av2 * sdt), __expf(Av3 * sdt));
}

__global__ __launch_bounds__(256) void scan_pass2(
    float* __restrict__ q, const float* __restrict__ P)
{
    const int idx = blockIdx.x * 256 + threadIdx.x;
    const int bd = idx >> 6, s = idx & 63;
    float H = 0.f;
    size_t o = (size_t)bd * NCH * DSTATE + s;
    for (int c = 0; c < NCH; ++c, o += DSTATE) {
        float qq = q[o], pp = P[o];
        q[o] = H;
        H = qq + pp * H;
    }
}

__global__ __launch_bounds__(256) void scan_pass3(
    const float* __restrict__ dtT, const float* __restrict__ dtuT,
    const float* __restrict__ xd, const float* __restrict__ A_log,
    const float* __restrict__ Hs, float* __restrict__ y)
{
    __shared__ float BCs[32 * 132];   // [t][B 0..63 | C 64..127], 32-step half
    const int tid = threadIdx.x;
    const int bx = blockIdx.x;
    const int dg = bx & 127;
    const int c  = (bx >> 7) & (NCH - 1);
    const int b  = bx >> 11;
    const int m0 = b * SEQLEN + c * CLEN;

    const int w = tid >> 6, l = tid & 63;
    const int d  = dg * 16 + w * 4 + (l >> 4);
    const int s0 = (l & 15) * 4;
    const bool lead = (l & 15) == 0;

    float4 Al = *(const float4*)&A_log[d * DSTATE + s0];
    const float Av0 = -expf(Al.x), Av1 = -expf(Al.y);
    const float Av2 = -expf(Al.z), Av3 = -expf(Al.w);

    const float* dtp  = dtT  + ((size_t)b * DINNER + d) * SEQLEN + c * CLEN;
    const float* dtup = dtuT + ((size_t)b * DINNER + d) * SEQLEN + c * CLEN;
    float* yp = y + (size_t)m0 * DINNER + d;

    float4 h4 = *(const float4*)&Hs[(((size_t)b * DINNER + d) * NCH + c) * DSTATE + s0];
    float h0 = h4.x, h1 = h4.y, h2 = h4.z, h3 = h4.w;

    // staging coords: 256 threads cover 32 rows x 128 floats (16 floats/thread)
    const int sr = tid >> 3;            // 0..31
    const int sc = (tid & 7) * 16;      // 0,16,...,112

#pragma unroll
    for (int half = 0; half < 2; ++half) {
        {   // stage rows [half*32, half*32+32) of B|C
            const float* src = xd + (size_t)(m0 + half * 32 + sr) * XDBL_N + DTRANK + sc;
            float* dst = &BCs[sr * 132 + sc];
#pragma unroll
            for (int ii = 0; ii < 4; ++ii)
                *(float4*)(dst + ii * 4) = *(const float4*)(src + ii * 4);
        }
        __syncthreads();

#pragma unroll
        for (int t4 = 0; t4 < 32; t4 += 4) {
            const int tt = half * 32 + t4;
            float4 d4 = *(const float4*)(dtp + tt);
            float4 g4 = *(const float4*)(dtup + tt);
#pragma unroll
            for (int k = 0; k < 4; ++k) {
                float dts = (k == 0) ? d4.x : (k == 1) ? d4.y : (k == 2) ? d4.z : d4.w;
                float gts = (k == 0) ? g4.x : (k == 1) ? g4.y : (k == 2) ? g4.z : g4.w;
                float4 Bv = *(const float4*)&BCs[(t4 + k) * 132 + s0];
                float4 Cv = *(const float4*)&BCs[(t4 + k) * 132 + 64 + s0];
                h0 = h0 * __expf(dts * Av0) + gts * Bv.x;
                h1 = h1 * __expf(dts * Av1) + gts * Bv.y;
                h2 = h2 * __expf(dts * Av2) + gts * Bv.z;
                h3 = h3 * __expf(dts * Av3) + gts * Bv.w;
                float v = h0 * Cv.x + h1 * Cv.y + h2 * Cv.z + h3 * Cv.w;
                float r = ror_sum16(v);
                if (lead) yp[(tt + k) * DINNER] = r;
            }
        }
        __syncthreads();
    }
}

// ---------------------------------------------------------------------------
// Gate + skip: y_bf = (y_scan + u*Dk) * silu(z)
// ---------------------------------------------------------------------------
__global__ __launch_bounds__(256) void gate_kernel(
    const float* __restrict__ y, const float* __restrict__ xz,
    const float* __restrict__ u, const float* __restrict__ D_skip,
    bf16* __restrict__ yb16)
{
    int idx = blockIdx.x * 256 + threadIdx.x;
    if (idx >= BL * DINNER) return;
    int d = idx & (DINNER - 1);
    int m = idx >> 11;
    float z = xz[(size_t)m * XZ_N + DINNER + d];
    float val = (y[idx] + u[idx] * D_skip[d]) * z / (1.f + expf(-z));
    yb16[idx] = __float2bfloat16(val);
}

// ---------------------------------------------------------------------------
extern "C" void kernel_launch(void* const* d_in, const int* in_sizes, int n_in,
                              void* d_out, int out_size, void* d_ws, size_t ws_size,
                              hipStream_t stream)
{
    const float* x     = (const float*)d_in[0];
    const float* in_w  = (const float*)d_in[1];
    const float* cw    = (const float*)d_in[2];
    const float* cb    = (const float*)d_in[3];
    const float* xp_w  = (const float*)d_in[4];
    const float* dt_w  = (const float*)d_in[5];
    const float* dt_b  = (const float*)d_in[6];
    const float* A_log = (const float*)d_in[7];
    const float* D_sk  = (const float*)d_in[8];
    const float* out_w = (const float*)d_in[9];
    float* out_final = (float*)d_out;

    float* ws = (float*)d_ws;
    float* xz    = ws;                                // [2048,4096]
    float* ub    = xz   + (size_t)BL * XZ_N;          // [2048,2048]
    float* xd    = ub   + (size_t)BL * DINNER;        // [2048,192]
    float* yb    = xd   + (size_t)BL * XDBL_N;        // [2048,2048] (also SK partials)
    float* lay   = yb   + (size_t)BL * DINNER;        // [2048,1024]
    float* dtT   = lay  + (size_t)BL * DMODEL;        // [2,2048,1024]
    float* dtuT  = dtT  + (size_t)BL * DINNER;        // [2,2048,1024]

    float* skp = yb;   // split-K partials [8][2048][192] = 12.6 MB <= yb's 16.8 MB

    bf16* bp = (bf16*)(dtuT + (size_t)BL * DINNER);
    bf16* inw_bf  = bp;  bp += (size_t)NLAYERS * XZ_N * DMODEL;
    bf16* outw_bf = bp;  bp += (size_t)NLAYERS * DMODEL * DINNER;
    bf16* xpw_bf  = bp;  bp += (size_t)NLAYERS * XDBL_N * DINNER;
    bf16* xin_bf  = bp;  bp += (size_t)BL * DMODEL;
    bf16* y_bf    = bp;  bp += (size_t)BL * DINNER;
    bf16* u_bf    = bp;  bp += (size_t)BL * DINNER;

    float* qbuf = (float*)bp;                              // [4096,16,64]
    float* Pbuf = qbuf + (size_t)BATCH * DINNER * NCH * DSTATE;

    {
        int n4 = NLAYERS * XZ_N * DMODEL / 4;
        cvt_bf16_kernel<<<(n4 + 255) / 256, 256, 0, stream>>>(in_w, inw_bf, n4);
        n4 = NLAYERS * DMODEL * DINNER / 4;
        cvt_bf16_kernel<<<(n4 + 255) / 256, 256, 0, stream>>>(out_w, outw_bf, n4);
        n4 = NLAYERS * XDBL_N * DINNER / 4;
        cvt_bf16_kernel<<<(n4 + 255) / 256, 256, 0, stream>>>(xp_w, xpw_bf, n4);
        n4 = BL * DMODEL / 4;
        cvt_bf16_kernel<<<(n4 + 255) / 256, 256, 0, stream>>>(x, xin_bf, n4);
    }

    for (int layer = 0; layer < NLAYERS; ++layer) {
        float* outp = (layer == NLAYERS - 1) ? out_final : lay;

        // 1. xz = xin @ in_w^T  (bf16 MFMA)
        gemm_mfma<false><<<dim3(XZ_N / 128, BL / 128), 256, 0, stream>>>(
            xin_bf, DMODEL, inw_bf + (size_t)layer * XZ_N * DMODEL,
            DMODEL, xz, nullptr, XZ_N, DMODEL);

        // 2. u = silu(dwconv(xz[:, :2048]))  (f32 + bf16 copies)
        conv_silu_kernel<<<(BL * DINNER) / 256, 256, 0, stream>>>(
            xz, cw + (size_t)layer * DINNER * 4, cb + (size_t)layer * DINNER,
            ub, u_bf);

        // 3. x_dbl = u @ xp_w^T  (bf16 MFMA split-K + deterministic f32 reduce)
        gemm_xp_mfma<<<dim3(XDBL_N / 64, BL / 128, SKN), 256, 0, stream>>>(
            u_bf, xpw_bf + (size_t)layer * XDBL_N * DINNER, skp);
        reduce_xd<<<(BL * XDBL_N / 4 + 255) / 256, 256, 0, stream>>>(skp, xd);

        // 4. dt = softplus(...); writes dtT and dtuT (= dt*u) transposed
        gemm_nt<1><<<dim3(DINNER / 64, BL / 64), 256, 0, stream>>>(
            xd, XDBL_N, dt_w + (size_t)layer * DINNER * DTRANK,
            dt_b + (size_t)layer * DINNER, nullptr, DINNER, DTRANK,
            ub, dtT, dtuT);

        // 5. chunked selective scan -> yb
        scan_pass1<<<BATCH * NCH * (DINNER / 16), 256, 0, stream>>>(
            dtT, dtuT, xd, A_log + (size_t)layer * DINNER * DSTATE, qbuf, Pbuf);
        scan_pass2<<<BATCH * DINNER * DSTATE / 256, 256, 0, stream>>>(qbuf, Pbuf);
        scan_pass3<<<BATCH * NCH * (DINNER / 16), 256, 0, stream>>>(
            dtT, dtuT, xd, A_log + (size_t)layer * DINNER * DSTATE, qbuf, yb);

        // 6. y_bf = (yb + u*Dk) * silu(z)
        gate_kernel<<<(BL * DINNER) / 256, 256, 0, stream>>>(
            yb, xz, ub, D_sk + (size_t)layer * DINNER, y_bf);

        // 7. out = y @ out_w^T  (bf16 MFMA)
        if (layer == NLAYERS - 1)
            gemm_mfma<false><<<dim3(DMODEL / 128, BL / 128), 256, 0, stream>>>(
                y_bf, DINNER, outw_bf + (size_t)layer * DMODEL * DINNER,
                DINNER, outp, nullptr, DMODEL, DINNER);
        else
            gemm_mfma<true><<<dim3(DMODEL / 128, BL / 128), 256, 0, stream>>>(
                y_bf, DINNER, outw_bf + (size_t)layer * DMODEL * DINNER,
                DINNER, outp, xin_bf, DMODEL, DINNER);
    }
}